// Round 3
// baseline (376.083 us; speedup 1.0000x reference)
//
#include <hip/hip_runtime.h>
#include <math.h>

#define NN 20000
#define EE 100000
#define CC 256
#define EDM 16
#define RC 4
#define MTOT (RC * NN)   // 80000

typedef __attribute__((ext_vector_type(8))) short short8;
typedef __attribute__((ext_vector_type(4))) float floatx4;

__device__ __forceinline__ unsigned short f2bf(float f) {
    union { float f; unsigned u; } v; v.f = f;
    unsigned r = v.u + 0x7FFF + ((v.u >> 16) & 1);   // RNE
    return (unsigned short)(r >> 16);
}
__device__ __forceinline__ float uif(unsigned u) {
    union { unsigned u; float f; } v; v.u = u;
    return v.f;
}

// GELU via A&S 7.1.27: erf(z) ~= 1 - (1 + a1 z + a2 z^2 + a3 z^3 + a4 z^4)^-4
// |erf err| <= 5e-4. Sign-free: gelu(v) = 0.5v + 0.5|v|*erf(|v|/sqrt2).
// 9 VALU + 1 TRANS (rcp) vs 13 VALU + 2 TRANS for the 7.1.26 form.
__device__ __forceinline__ float gelu27(float v) {
    const float z  = fabsf(v) * 0.70710678118654752f;
    const float P  = fmaf(z, fmaf(z, fmaf(z, fmaf(z, 0.078108f, 0.000972f),
                           0.230389f), 0.278393f), 1.0f);
    const float r  = __builtin_amdgcn_rcpf(P);
    const float r2 = r * r;
    const float r4 = r2 * r2;
    const float h  = 0.5f * fabsf(v);
    return fmaf(0.5f, v, fmaf(-h, r4, h));   // 0.5v + h*(1 - r^4)
}

// async global->LDS, 16B per lane; LDS dest is wave-uniform base + lane*16
#define GLDS16(gp, lp)                                                        \
    __builtin_amdgcn_global_load_lds(                                         \
        (const __attribute__((address_space(1))) unsigned int*)(gp),          \
        (__attribute__((address_space(3))) unsigned int*)(lp), 16, 0, 0)

// ---------------------------------------------------------------------------
// fused prep (weight transpose+bf16) + per-dst edge count
// ---------------------------------------------------------------------------
__global__ void k_prep_count(const float* __restrict__ lin_W,
                             const float* __restrict__ linl_W,
                             const float* __restrict__ linr_W,
                             unsigned short* __restrict__ linWT,
                             unsigned short* __restrict__ WbT,
                             const int* __restrict__ eidx,
                             int* __restrict__ cnt) {
    const int b = blockIdx.x;
    const int t = threadIdx.x;
    if (b < CC) {
        linWT[b * CC + t]      = f2bf(lin_W[t * CC + b]);
        WbT[b * 512 + t]       = f2bf(linl_W[t * CC + b]);
        WbT[b * 512 + 256 + t] = f2bf(linr_W[t * CC + b]);
    } else {
        int e = (b - CC) * 256 + t;
        if (e < EE) atomicAdd(cnt + eidx[EE + e], 1);
    }
}

// ---------------------------------------------------------------------------
// m97-style MFMA GEMM: C[M x 256] = concat_k(A1, A2)[M x KTOT] @ B[KTOT x 256]
// 256 threads, 128x128 tile, BK=64, grid (M/128, 2).
// B (and A1 when A1BF16) staged via global_load_lds, linear LDS [128][64].
// A fp32 halves reg-staged with f2bf.
// OUTBF16=1 writes rc-interleaved bf16: Cb[(n*CC+col)*4 + rc], rc=row/NN.
// ---------------------------------------------------------------------------
template <int KTOT, int OUTBF16, int A1BF16>
__global__ __launch_bounds__(256) void k_mmb(const float* __restrict__ A1f,
                                             const unsigned short* __restrict__ A1b,
                                             const float* __restrict__ A2f,
                                             const unsigned short* __restrict__ BT,
                                             const float* __restrict__ bias,
                                             float* __restrict__ Cf,
                                             unsigned short* __restrict__ Cb) {
    __shared__ unsigned short As[128 * 64];
    __shared__ unsigned short Bs[128 * 64];
    const int tid  = threadIdx.x;
    const int lane = tid & 63;
    const int wave = tid >> 6;      // 0..3
    const int wr   = wave >> 1;     // 0..1  (64-row half)
    const int wc   = wave & 1;      // 0..1  (64-col half)
    const int l15  = lane & 15;
    const int q4   = lane >> 4;
    const int lr8  = lane >> 3;     // row within an 8-row glds group
    const int lc8  = lane & 7;      // 16B slot within a 128B row
    const int i0   = blockIdx.x * 128;
    const int n0   = blockIdx.y * 128;

    floatx4 acc[4][4];
#pragma unroll
    for (int mt = 0; mt < 4; mt++)
#pragma unroll
        for (int nt = 0; nt < 4; nt++) acc[mt][nt] = (floatx4)0.0f;

    for (int kc = 0; kc < KTOT; kc += 64) {
        __syncthreads();
        const int first = (kc < 256);
        const int kco   = first ? kc : kc - 256;
        // ---- B tile: rows n0..n0+127, cols kc..kc+63 (bf16, row stride KTOT)
#pragma unroll
        for (int it = 0; it < 4; it++) {
            const int op = wave * 4 + it;    // 0..15, 8 rows each
            const unsigned short* g =
                BT + (size_t)(n0 + op * 8 + lr8) * KTOT + kc + lc8 * 8;
            GLDS16(g, Bs + op * 512);
        }
        // ---- A tile: rows i0..i0+127, cols kco..kco+63
        if (A1BF16 && first) {
#pragma unroll
            for (int it = 0; it < 4; it++) {
                const int op = wave * 4 + it;
                const unsigned short* g =
                    A1b + (size_t)(i0 + op * 8 + lr8) * CC + kc + lc8 * 8;
                GLDS16(g, As + op * 512);
            }
        } else {
            const float* af = first ? A1f : A2f;
#pragma unroll
            for (int w = 0; w < 4; w++) {
                const int q  = w * 256 + tid;   // 0..1023 16B-slots
                const int r  = q >> 3;          // row 0..127
                const int c8 = q & 7;           // 16B col
                const float* s = af + (size_t)(i0 + r) * CC + kco + c8 * 8;
                float4 v0 = *(const float4*)(s);
                float4 v1 = *(const float4*)(s + 4);
                uint4 p;
                p.x = (unsigned)f2bf(v0.x) | ((unsigned)f2bf(v0.y) << 16);
                p.y = (unsigned)f2bf(v0.z) | ((unsigned)f2bf(v0.w) << 16);
                p.z = (unsigned)f2bf(v1.x) | ((unsigned)f2bf(v1.y) << 16);
                p.w = (unsigned)f2bf(v1.z) | ((unsigned)f2bf(v1.w) << 16);
                *(uint4*)(As + r * 64 + c8 * 8) = p;
            }
        }
        __syncthreads();   // drains vmcnt(0): glds landed
#pragma unroll
        for (int kk = 0; kk < 64; kk += 32) {
            short8 a[4], b[4];
#pragma unroll
            for (int mt = 0; mt < 4; mt++)
                a[mt] = *(const short8*)(As + (wr * 64 + mt * 16 + l15) * 64 + kk + q4 * 8);
#pragma unroll
            for (int nt = 0; nt < 4; nt++)
                b[nt] = *(const short8*)(Bs + (wc * 64 + nt * 16 + l15) * 64 + kk + q4 * 8);
#pragma unroll
            for (int mt = 0; mt < 4; mt++)
#pragma unroll
                for (int nt = 0; nt < 4; nt++)
                    acc[mt][nt] = __builtin_amdgcn_mfma_f32_16x16x32_bf16(
                        a[mt], b[nt], acc[mt][nt], 0, 0, 0);
        }
    }
    // C/D layout: col=lane&15, row=(lane>>4)*4+reg  [verified m89/m91]
#pragma unroll
    for (int nt = 0; nt < 4; nt++) {
        const int col = n0 + wc * 64 + nt * 16 + l15;
        const float bz = bias[col];
#pragma unroll
        for (int mt = 0; mt < 4; mt++) {
#pragma unroll
            for (int r = 0; r < 4; r++) {
                const int row = i0 + wr * 64 + mt * 16 + q4 * 4 + r;
                const float v = acc[mt][nt][r] + bz;
                if (OUTBF16) {
                    const unsigned rc = (unsigned)row / (unsigned)NN;
                    const unsigned nn = (unsigned)row - rc * (unsigned)NN;
                    Cb[((size_t)nn * CC + col) * 4 + rc] = f2bf(v);
                } else {
                    Cf[(size_t)row * CC + col] = v;
                }
            }
        }
    }
}

// ---------------------------------------------------------------------------
// CSR scan + scatter
// ---------------------------------------------------------------------------
#define SCAN_T 1024
#define SCHUNK 20
__global__ __launch_bounds__(1024) void k_scan(const int* __restrict__ cnt,
                                               int* __restrict__ offs,
                                               int* __restrict__ cursor) {
    __shared__ int ps[SCAN_T];
    const int t = threadIdx.x;
    const int base = t * SCHUNK;
    int s = 0;
#pragma unroll
    for (int i = 0; i < SCHUNK; i++) {
        int idx = base + i;
        if (idx < NN) s += cnt[idx];
    }
    ps[t] = s;
    __syncthreads();
    for (int off = 1; off < SCAN_T; off <<= 1) {
        int v = (t >= off) ? ps[t - off] : 0;
        __syncthreads();
        ps[t] += v;
        __syncthreads();
    }
    int excl = (t == 0) ? 0 : ps[t - 1];
#pragma unroll
    for (int i = 0; i < SCHUNK; i++) {
        int idx = base + i;
        if (idx < NN) {
            offs[idx]   = excl;
            cursor[idx] = excl;
            excl += cnt[idx];
        }
    }
    if (t == SCAN_T - 1) offs[NN] = ps[SCAN_T - 1];
}

// scatter + build edge-ordered side arrays: srcb[p], ewb[p] = 4 weights of e
__global__ void k_scatter(const int* __restrict__ eidx,
                          const float* __restrict__ ew,
                          int* __restrict__ cursor,
                          int* __restrict__ bucket,
                          int* __restrict__ srcb,
                          float4* __restrict__ ewb) {
    int e = blockIdx.x * 256 + threadIdx.x;
    if (e < EE) {
        int d = eidx[EE + e];
        int p = atomicAdd(cursor + d, 1);
        bucket[p] = e;
        srcb[p]   = eidx[e];
        ewb[p]    = make_float4(ew[e], ew[EE + e], ew[2 * EE + e], ew[3 * EE + e]);
    }
}

// ---------------------------------------------------------------------------
// gather-mean: block = node, thread = channel, 4 rc accumulators per lane.
// xlb4 is rc-interleaved [n][c][rc] -> one uint2 (8B) load per edge.
// srcb/ewb are bucket-ordered (sequential). edge_attr read as 4x float4.
// ---------------------------------------------------------------------------
__global__ __launch_bounds__(256) void k_agg(const unsigned short* __restrict__ xlb4,
                                             const float* __restrict__ edge_attr,
                                             const float4* __restrict__ ewb,
                                             const float* __restrict__ bond_W,
                                             const float* __restrict__ bond_b,
                                             const int* __restrict__ srcb,
                                             const int* __restrict__ offs,
                                             const int* __restrict__ bucket,
                                             unsigned short* __restrict__ mean_b) {
    const int n = blockIdx.x;
    const int c = threadIdx.x;
    const int beg = offs[n], end = offs[n + 1];
    const float bb = bond_b[c];
    float bw[EDM];
#pragma unroll
    for (int k = 0; k < EDM; k++) bw[k] = bond_W[k * CC + c];   // loop-invariant

    float a0 = 0.f, a1 = 0.f, a2 = 0.f, a3 = 0.f;

#pragma unroll 2
    for (int j = beg; j < end; j++) {
        const int e     = bucket[j];
        const int src   = srcb[j];
        const float4 w  = ewb[j];
        const float4* ea4 = (const float4*)(edge_attr + (size_t)e * EDM);
        const float4 q0 = ea4[0], q1 = ea4[1], q2 = ea4[2], q3 = ea4[3];
        float emb = bb;
        emb = fmaf(q0.x, bw[0],  emb); emb = fmaf(q0.y, bw[1],  emb);
        emb = fmaf(q0.z, bw[2],  emb); emb = fmaf(q0.w, bw[3],  emb);
        emb = fmaf(q1.x, bw[4],  emb); emb = fmaf(q1.y, bw[5],  emb);
        emb = fmaf(q1.z, bw[6],  emb); emb = fmaf(q1.w, bw[7],  emb);
        emb = fmaf(q2.x, bw[8],  emb); emb = fmaf(q2.y, bw[9],  emb);
        emb = fmaf(q2.z, bw[10], emb); emb = fmaf(q2.w, bw[11], emb);
        emb = fmaf(q3.x, bw[12], emb); emb = fmaf(q3.y, bw[13], emb);
        emb = fmaf(q3.z, bw[14], emb); emb = fmaf(q3.w, bw[15], emb);
        const uint2 u = *(const uint2*)(xlb4 + ((size_t)src * CC + c) * 4);
        const float v0 = uif(u.x << 16)          + emb;
        const float v1 = uif(u.x & 0xffff0000u)  + emb;
        const float v2 = uif(u.y << 16)          + emb;
        const float v3 = uif(u.y & 0xffff0000u)  + emb;
        a0 = fmaf(gelu27(v0), w.x, a0);
        a1 = fmaf(gelu27(v1), w.y, a1);
        a2 = fmaf(gelu27(v2), w.z, a2);
        a3 = fmaf(gelu27(v3), w.w, a3);
    }
    const float inv = 1.0f / fmaxf((float)(end - beg), 1.0f);
    const size_t ob = (size_t)n * CC + c;
    mean_b[ob]                       = f2bf(a0 * inv);
    mean_b[ob + (size_t)NN * CC]     = f2bf(a1 * inv);
    mean_b[ob + (size_t)2 * NN * CC] = f2bf(a2 * inv);
    mean_b[ob + (size_t)3 * NN * CC] = f2bf(a3 * inv);
}

extern "C" void kernel_launch(void* const* d_in, const int* in_sizes, int n_in,
                              void* d_out, int out_size, void* d_ws, size_t ws_size,
                              hipStream_t stream) {
    (void)in_sizes; (void)n_in; (void)out_size; (void)ws_size;
    const float* x           = (const float*)d_in[0];
    const float* edge_attr   = (const float*)d_in[1];
    const float* edge_weight = (const float*)d_in[2];
    const float* lin_W       = (const float*)d_in[3];
    const float* lin_b       = (const float*)d_in[4];
    const float* linl_W      = (const float*)d_in[5];
    const float* linl_b      = (const float*)d_in[6];
    const float* linr_W      = (const float*)d_in[7];
    const float* bond_W      = (const float*)d_in[8];
    const float* bond_b      = (const float*)d_in[9];
    const int*   edge_index  = (const int*)d_in[10];

    unsigned short* xlb   = (unsigned short*)d_ws;          // 80000*256 bf16 (rc-interleaved)
    unsigned short* linWT = xlb + (size_t)MTOT * CC;        // 256*256 bf16
    unsigned short* WbT   = linWT + CC * CC;                // 256*512 bf16
    int* cnt    = (int*)(WbT + CC * 512);                   // N
    int* offs   = cnt + NN;                                 // N+1
    int* cursor = offs + NN + 1;                            // N
    int* bucket = cursor + NN;                              // E
    uintptr_t mb_addr = (((uintptr_t)(bucket + EE)) + 255) & ~(uintptr_t)255;
    unsigned short* mean_b = (unsigned short*)mb_addr;      // 80000*256 bf16

    // scratch in d_out: dead once k_mmb<512> runs (it overwrites ALL of d_out)
    float4* ewb = (float4*)d_out;                           // E * 16B = 1.6 MB
    int*    srcb = (int*)(ewb + EE);                        // E * 4B

    hipMemsetAsync(cnt, 0, NN * sizeof(int), stream);

    k_prep_count<<<CC + (EE + 255) / 256, 256, 0, stream>>>(
        lin_W, linl_W, linr_W, linWT, WbT, edge_index, cnt);
    // x_l(bf16, rc-interleaved) = x @ lin_W + lin_b
    k_mmb<256, 1, 0><<<dim3(MTOT / 128, 2), 256, 0, stream>>>(
        x, nullptr, nullptr, linWT, lin_b, nullptr, xlb);
    k_scan<<<1, SCAN_T, 0, stream>>>(cnt, offs, cursor);
    k_scatter<<<(EE + 255) / 256, 256, 0, stream>>>(edge_index, edge_weight,
                                                    cursor, bucket, srcb, ewb);
    k_agg<<<NN, 256, 0, stream>>>(xlb, edge_attr, ewb, bond_W, bond_b,
                                  srcb, offs, bucket, mean_b);
    // out = [mean | x] @ [linl; linr] + linl_b   (mean half via glds, x reg-staged)
    k_mmb<512, 0, 1><<<dim3(MTOT / 128, 2), 256, 0, stream>>>(
        nullptr, mean_b, x, WbT, linl_b, (float*)d_out, nullptr);
}

// Round 4
// 356.817 us; speedup vs baseline: 1.0540x; 1.0540x over previous
//
#include <hip/hip_runtime.h>
#include <math.h>

#define NN 20000
#define EE 100000
#define CC 256
#define EDM 16
#define RC 4
#define MTOT (RC * NN)   // 80000

typedef __attribute__((ext_vector_type(8))) short short8;
typedef __attribute__((ext_vector_type(4))) float floatx4;

__device__ __forceinline__ unsigned short f2bf(float f) {
    union { float f; unsigned u; } v; v.f = f;
    unsigned r = v.u + 0x7FFF + ((v.u >> 16) & 1);   // RNE
    return (unsigned short)(r >> 16);
}
__device__ __forceinline__ float uif(unsigned u) {
    union { unsigned u; float f; } v; v.u = u;
    return v.f;
}

// GELU via A&S 7.1.27: erf(z) ~= 1 - (1 + a1 z + a2 z^2 + a3 z^3 + a4 z^4)^-4
__device__ __forceinline__ float gelu27(float v) {
    const float z  = fabsf(v) * 0.70710678118654752f;
    const float P  = fmaf(z, fmaf(z, fmaf(z, fmaf(z, 0.078108f, 0.000972f),
                           0.230389f), 0.278393f), 1.0f);
    const float r  = __builtin_amdgcn_rcpf(P);
    const float r2 = r * r;
    const float r4 = r2 * r2;
    const float h  = 0.5f * fabsf(v);
    return fmaf(0.5f, v, fmaf(-h, r4, h));   // 0.5v + h*(1 - r^4)
}

// async global->LDS, 16B per lane; LDS dest is wave-uniform base + lane*16
#define GLDS16(gp, lp)                                                        \
    __builtin_amdgcn_global_load_lds(                                         \
        (const __attribute__((address_space(1))) unsigned int*)(gp),          \
        (__attribute__((address_space(3))) unsigned int*)(lp), 16, 0, 0)

// ---------------------------------------------------------------------------
// fused prep (weight transpose+bf16) + per-dst edge count
// ---------------------------------------------------------------------------
__global__ void k_prep_count(const float* __restrict__ lin_W,
                             const float* __restrict__ linl_W,
                             const float* __restrict__ linr_W,
                             unsigned short* __restrict__ linWT,
                             unsigned short* __restrict__ WbT,
                             const int* __restrict__ eidx,
                             int* __restrict__ cnt) {
    const int b = blockIdx.x;
    const int t = threadIdx.x;
    if (b < CC) {
        linWT[b * CC + t]      = f2bf(lin_W[t * CC + b]);
        WbT[b * 512 + t]       = f2bf(linl_W[t * CC + b]);
        WbT[b * 512 + 256 + t] = f2bf(linr_W[t * CC + b]);
    } else {
        int e = (b - CC) * 256 + t;
        if (e < EE) atomicAdd(cnt + eidx[EE + e], 1);
    }
}

// ---------------------------------------------------------------------------
// mm1: xlb4[n][c][rc] (bf16, rc-interleaved) = x @ lin_W + lin_b
// M-tile = 32 nodes x 4 rc = 128 rows: local row r -> global (r>>5)*NN+nn0+(r&31)
// Epilogue staged through LDS -> fully coalesced 16B stores (no write amp).
// Side-product (grid.y==0): xb = bf16(x), planar [row][256], for mm2's glds.
// ---------------------------------------------------------------------------
__global__ __launch_bounds__(256) void k_mm1(const float* __restrict__ x,
                                             const unsigned short* __restrict__ linWT,
                                             const float* __restrict__ lin_b,
                                             unsigned short* __restrict__ xlb4,
                                             unsigned short* __restrict__ xb) {
    __shared__ unsigned short SH[2][128 * 64];   // As=SH[0], Bs=SH[1]; 32 KB total
    unsigned short* As = SH[0];
    unsigned short* Bs = SH[1];
    const int tid  = threadIdx.x;
    const int lane = tid & 63;
    const int wave = tid >> 6;      // 0..3
    const int wr   = wave >> 1;     // 0..1  (64-row half)
    const int wc   = wave & 1;      // 0..1  (64-col half)
    const int l15  = lane & 15;
    const int q4   = lane >> 4;
    const int lr8  = lane >> 3;
    const int lc8  = lane & 7;
    const int nn0  = blockIdx.x * 32;
    const int n0h  = blockIdx.y * 128;
    const int emit_xb = (xb != nullptr) && (blockIdx.y == 0);

    floatx4 acc[4][4];
#pragma unroll
    for (int mt = 0; mt < 4; mt++)
#pragma unroll
        for (int nt = 0; nt < 4; nt++) acc[mt][nt] = (floatx4)0.0f;

    for (int kc = 0; kc < 256; kc += 64) {
        __syncthreads();
        // B tile: linWT rows n0h..+127 (out cols), k cols kc..+63, stride 256
#pragma unroll
        for (int it = 0; it < 4; it++) {
            const int op = wave * 4 + it;
            const unsigned short* g =
                linWT + (size_t)(n0h + op * 8 + lr8) * CC + kc + lc8 * 8;
            GLDS16(g, Bs + op * 512);
        }
        // A tile: fp32 x rows g(r), reg-staged with f2bf; side-store xb
#pragma unroll
        for (int w = 0; w < 4; w++) {
            const int q  = w * 256 + tid;
            const int r  = q >> 3;
            const int c8 = q & 7;
            const int grow = (r >> 5) * NN + nn0 + (r & 31);
            const float* s = x + (size_t)grow * CC + kc + c8 * 8;
            float4 v0 = *(const float4*)(s);
            float4 v1 = *(const float4*)(s + 4);
            uint4 p;
            p.x = (unsigned)f2bf(v0.x) | ((unsigned)f2bf(v0.y) << 16);
            p.y = (unsigned)f2bf(v0.z) | ((unsigned)f2bf(v0.w) << 16);
            p.z = (unsigned)f2bf(v1.x) | ((unsigned)f2bf(v1.y) << 16);
            p.w = (unsigned)f2bf(v1.z) | ((unsigned)f2bf(v1.w) << 16);
            *(uint4*)(As + r * 64 + c8 * 8) = p;
            if (emit_xb)
                *(uint4*)(xb + (size_t)grow * CC + kc + c8 * 8) = p;
        }
        __syncthreads();
#pragma unroll
        for (int kk = 0; kk < 64; kk += 32) {
            short8 a[4], b[4];
#pragma unroll
            for (int mt = 0; mt < 4; mt++)
                a[mt] = *(const short8*)(As + (wr * 64 + mt * 16 + l15) * 64 + kk + q4 * 8);
#pragma unroll
            for (int nt = 0; nt < 4; nt++)
                b[nt] = *(const short8*)(Bs + (wc * 64 + nt * 16 + l15) * 64 + kk + q4 * 8);
#pragma unroll
            for (int mt = 0; mt < 4; mt++)
#pragma unroll
                for (int nt = 0; nt < 4; nt++)
                    acc[mt][nt] = __builtin_amdgcn_mfma_f32_16x16x32_bf16(
                        a[mt], b[nt], acc[mt][nt], 0, 0, 0);
        }
    }
    // ---- epilogue: stage [i(32)][cl(128)][rc(4)] bf16 = 32 KB in SH, then
    // coalesced 16B global stores. row = wr*64+mt*16+q4*4+rr ->
    // i = (mt&1)*16+q4*4+rr, rc = wr*2+(mt>>1): pack (mt, mt+2) as b32.
    __syncthreads();
    char* E = (char*)SH;
#pragma unroll
    for (int nt = 0; nt < 4; nt++) {
        const int cl = wc * 64 + nt * 16 + l15;
        const float bz = lin_b[n0h + cl];
#pragma unroll
        for (int m0 = 0; m0 < 2; m0++) {
#pragma unroll
            for (int rr = 0; rr < 4; rr++) {
                const int i = m0 * 16 + q4 * 4 + rr;
                const unsigned lo = f2bf(acc[m0][nt][rr] + bz);
                const unsigned hi = f2bf(acc[m0 + 2][nt][rr] + bz);
                *(unsigned*)(E + i * 1024 + cl * 8 + wr * 4) = lo | (hi << 16);
            }
        }
    }
    __syncthreads();
    char* gbase = (char*)xlb4 + (size_t)nn0 * 2048 + (size_t)n0h * 8;
#pragma unroll
    for (int p = 0; p < 8; p++) {
        const int idx = p * 256 + tid;
        const int i   = idx >> 6;
        const int w   = (idx & 63) * 16;
        uint4 v = *(const uint4*)(E + i * 1024 + w);
        *(uint4*)(gbase + (size_t)i * 2048 + w) = v;
    }
}

// ---------------------------------------------------------------------------
// mm2: out[row][col] fp32 = [mean | x] @ WbT^T + linl_b.  K=512.
// XB=1: both A halves bf16 via glds (mean_b, xb). XB=0: x reg-staged fp32.
// ---------------------------------------------------------------------------
template <int XB>
__global__ __launch_bounds__(256) void k_mm2(const unsigned short* __restrict__ mean_b,
                                             const unsigned short* __restrict__ xb,
                                             const float* __restrict__ xf,
                                             const unsigned short* __restrict__ WbT,
                                             const float* __restrict__ bias,
                                             float* __restrict__ out) {
    __shared__ unsigned short As[128 * 64];
    __shared__ unsigned short Bs[128 * 64];
    const int tid  = threadIdx.x;
    const int lane = tid & 63;
    const int wave = tid >> 6;
    const int wr   = wave >> 1;
    const int wc   = wave & 1;
    const int l15  = lane & 15;
    const int q4   = lane >> 4;
    const int lr8  = lane >> 3;
    const int lc8  = lane & 7;
    const int i0   = blockIdx.x * 128;
    const int n0   = blockIdx.y * 128;

    floatx4 acc[4][4];
#pragma unroll
    for (int mt = 0; mt < 4; mt++)
#pragma unroll
        for (int nt = 0; nt < 4; nt++) acc[mt][nt] = (floatx4)0.0f;

    for (int kc = 0; kc < 512; kc += 64) {
        __syncthreads();
        const int first = (kc < 256);
        const int kco   = first ? kc : kc - 256;
        // B tile: WbT rows n0..+127 (out cols), k cols kc..+63, stride 512
#pragma unroll
        for (int it = 0; it < 4; it++) {
            const int op = wave * 4 + it;
            const unsigned short* g =
                WbT + (size_t)(n0 + op * 8 + lr8) * 512 + kc + lc8 * 8;
            GLDS16(g, Bs + op * 512);
        }
        // A tile
        if (first || XB) {
            const unsigned short* ab = first ? mean_b : xb;
#pragma unroll
            for (int it = 0; it < 4; it++) {
                const int op = wave * 4 + it;
                const unsigned short* g =
                    ab + (size_t)(i0 + op * 8 + lr8) * CC + kco + lc8 * 8;
                GLDS16(g, As + op * 512);
            }
        } else {
#pragma unroll
            for (int w = 0; w < 4; w++) {
                const int q  = w * 256 + tid;
                const int r  = q >> 3;
                const int c8 = q & 7;
                const float* s = xf + (size_t)(i0 + r) * CC + kco + c8 * 8;
                float4 v0 = *(const float4*)(s);
                float4 v1 = *(const float4*)(s + 4);
                uint4 p;
                p.x = (unsigned)f2bf(v0.x) | ((unsigned)f2bf(v0.y) << 16);
                p.y = (unsigned)f2bf(v0.z) | ((unsigned)f2bf(v0.w) << 16);
                p.z = (unsigned)f2bf(v1.x) | ((unsigned)f2bf(v1.y) << 16);
                p.w = (unsigned)f2bf(v1.z) | ((unsigned)f2bf(v1.w) << 16);
                *(uint4*)(As + r * 64 + c8 * 8) = p;
            }
        }
        __syncthreads();
#pragma unroll
        for (int kk = 0; kk < 64; kk += 32) {
            short8 a[4], b[4];
#pragma unroll
            for (int mt = 0; mt < 4; mt++)
                a[mt] = *(const short8*)(As + (wr * 64 + mt * 16 + l15) * 64 + kk + q4 * 8);
#pragma unroll
            for (int nt = 0; nt < 4; nt++)
                b[nt] = *(const short8*)(Bs + (wc * 64 + nt * 16 + l15) * 64 + kk + q4 * 8);
#pragma unroll
            for (int mt = 0; mt < 4; mt++)
#pragma unroll
                for (int nt = 0; nt < 4; nt++)
                    acc[mt][nt] = __builtin_amdgcn_mfma_f32_16x16x32_bf16(
                        a[mt], b[nt], acc[mt][nt], 0, 0, 0);
        }
    }
#pragma unroll
    for (int nt = 0; nt < 4; nt++) {
        const int col = n0 + wc * 64 + nt * 16 + l15;
        const float bz = bias[col];
#pragma unroll
        for (int mt = 0; mt < 4; mt++) {
#pragma unroll
            for (int r = 0; r < 4; r++) {
                const int row = i0 + wr * 64 + mt * 16 + q4 * 4 + r;
                out[(size_t)row * CC + col] = acc[mt][nt][r] + bz;
            }
        }
    }
}

// ---------------------------------------------------------------------------
// CSR scan + scatter
// ---------------------------------------------------------------------------
#define SCAN_T 1024
#define SCHUNK 20
__global__ __launch_bounds__(1024) void k_scan(const int* __restrict__ cnt,
                                               int* __restrict__ offs,
                                               int* __restrict__ cursor) {
    __shared__ int ps[SCAN_T];
    const int t = threadIdx.x;
    const int base = t * SCHUNK;
    int s = 0;
#pragma unroll
    for (int i = 0; i < SCHUNK; i++) {
        int idx = base + i;
        if (idx < NN) s += cnt[idx];
    }
    ps[t] = s;
    __syncthreads();
    for (int off = 1; off < SCAN_T; off <<= 1) {
        int v = (t >= off) ? ps[t - off] : 0;
        __syncthreads();
        ps[t] += v;
        __syncthreads();
    }
    int excl = (t == 0) ? 0 : ps[t - 1];
#pragma unroll
    for (int i = 0; i < SCHUNK; i++) {
        int idx = base + i;
        if (idx < NN) {
            offs[idx]   = excl;
            cursor[idx] = excl;
            excl += cnt[idx];
        }
    }
    if (t == SCAN_T - 1) offs[NN] = ps[SCAN_T - 1];
}

// scatter + build edge-ordered side arrays: srcb[p], ewb[p] = 4 weights of e
__global__ void k_scatter(const int* __restrict__ eidx,
                          const float* __restrict__ ew,
                          int* __restrict__ cursor,
                          int* __restrict__ bucket,
                          int* __restrict__ srcb,
                          float4* __restrict__ ewb) {
    int e = blockIdx.x * 256 + threadIdx.x;
    if (e < EE) {
        int d = eidx[EE + e];
        int p = atomicAdd(cursor + d, 1);
        bucket[p] = e;
        srcb[p]   = eidx[e];
        ewb[p]    = make_float4(ew[e], ew[EE + e], ew[2 * EE + e], ew[3 * EE + e]);
    }
}

// ---------------------------------------------------------------------------
// gather-mean: block = node, thread = channel, 4 rc accumulators per lane.
// ---------------------------------------------------------------------------
__global__ __launch_bounds__(256) void k_agg(const unsigned short* __restrict__ xlb4,
                                             const float* __restrict__ edge_attr,
                                             const float4* __restrict__ ewb,
                                             const float* __restrict__ bond_W,
                                             const float* __restrict__ bond_b,
                                             const int* __restrict__ srcb,
                                             const int* __restrict__ offs,
                                             const int* __restrict__ bucket,
                                             unsigned short* __restrict__ mean_b) {
    const int n = blockIdx.x;
    const int c = threadIdx.x;
    const int beg = offs[n], end = offs[n + 1];
    const float bb = bond_b[c];
    float bw[EDM];
#pragma unroll
    for (int k = 0; k < EDM; k++) bw[k] = bond_W[k * CC + c];

    float a0 = 0.f, a1 = 0.f, a2 = 0.f, a3 = 0.f;

#pragma unroll 2
    for (int j = beg; j < end; j++) {
        const int e     = bucket[j];
        const int src   = srcb[j];
        const float4 w  = ewb[j];
        const float4* ea4 = (const float4*)(edge_attr + (size_t)e * EDM);
        const float4 q0 = ea4[0], q1 = ea4[1], q2 = ea4[2], q3 = ea4[3];
        float emb = bb;
        emb = fmaf(q0.x, bw[0],  emb); emb = fmaf(q0.y, bw[1],  emb);
        emb = fmaf(q0.z, bw[2],  emb); emb = fmaf(q0.w, bw[3],  emb);
        emb = fmaf(q1.x, bw[4],  emb); emb = fmaf(q1.y, bw[5],  emb);
        emb = fmaf(q1.z, bw[6],  emb); emb = fmaf(q1.w, bw[7],  emb);
        emb = fmaf(q2.x, bw[8],  emb); emb = fmaf(q2.y, bw[9],  emb);
        emb = fmaf(q2.z, bw[10], emb); emb = fmaf(q2.w, bw[11], emb);
        emb = fmaf(q3.x, bw[12], emb); emb = fmaf(q3.y, bw[13], emb);
        emb = fmaf(q3.z, bw[14], emb); emb = fmaf(q3.w, bw[15], emb);
        const uint2 u = *(const uint2*)(xlb4 + ((size_t)src * CC + c) * 4);
        const float v0 = uif(u.x << 16)          + emb;
        const float v1 = uif(u.x & 0xffff0000u)  + emb;
        const float v2 = uif(u.y << 16)          + emb;
        const float v3 = uif(u.y & 0xffff0000u)  + emb;
        a0 = fmaf(gelu27(v0), w.x, a0);
        a1 = fmaf(gelu27(v1), w.y, a1);
        a2 = fmaf(gelu27(v2), w.z, a2);
        a3 = fmaf(gelu27(v3), w.w, a3);
    }
    const float inv = 1.0f / fmaxf((float)(end - beg), 1.0f);
    const size_t ob = (size_t)n * CC + c;
    mean_b[ob]                       = f2bf(a0 * inv);
    mean_b[ob + (size_t)NN * CC]     = f2bf(a1 * inv);
    mean_b[ob + (size_t)2 * NN * CC] = f2bf(a2 * inv);
    mean_b[ob + (size_t)3 * NN * CC] = f2bf(a3 * inv);
}

extern "C" void kernel_launch(void* const* d_in, const int* in_sizes, int n_in,
                              void* d_out, int out_size, void* d_ws, size_t ws_size,
                              hipStream_t stream) {
    (void)in_sizes; (void)n_in; (void)out_size;
    const float* x           = (const float*)d_in[0];
    const float* edge_attr   = (const float*)d_in[1];
    const float* edge_weight = (const float*)d_in[2];
    const float* lin_W       = (const float*)d_in[3];
    const float* lin_b       = (const float*)d_in[4];
    const float* linl_W      = (const float*)d_in[5];
    const float* linl_b      = (const float*)d_in[6];
    const float* linr_W      = (const float*)d_in[7];
    const float* bond_W      = (const float*)d_in[8];
    const float* bond_b      = (const float*)d_in[9];
    const int*   edge_index  = (const int*)d_in[10];

    unsigned short* xlb4  = (unsigned short*)d_ws;          // 80000*256 bf16 (rc-interleaved)
    unsigned short* linWT = xlb4 + (size_t)MTOT * CC;       // 256*256 bf16
    unsigned short* WbT   = linWT + CC * CC;                // 256*512 bf16
    int* cnt    = (int*)(WbT + CC * 512);                   // N
    int* offs   = cnt + NN;                                 // N+1
    int* cursor = offs + NN + 1;                            // N
    int* bucket = cursor + NN;                              // E
    uintptr_t mb_addr = (((uintptr_t)(bucket + EE)) + 255) & ~(uintptr_t)255;
    unsigned short* mean_b = (unsigned short*)mb_addr;      // 80000*256 bf16
    unsigned short* xb     = mean_b + (size_t)MTOT * CC;    // 80000*256 bf16 (optional)
    const size_t need_xb = ((uintptr_t)(xb + (size_t)MTOT * CC)) - (uintptr_t)d_ws;
    const int use_xb = (ws_size >= need_xb);

    // scratch in d_out: dead once k_mm2 runs (it overwrites ALL of d_out)
    float4* ewb  = (float4*)d_out;                          // E * 16B
    int*    srcb = (int*)(ewb + EE);                        // E * 4B

    hipMemsetAsync(cnt, 0, NN * sizeof(int), stream);

    k_prep_count<<<CC + (EE + 255) / 256, 256, 0, stream>>>(
        lin_W, linl_W, linr_W, linWT, WbT, edge_index, cnt);
    // xlb4 = x @ lin_W + lin_b (rc-interleaved); xb = bf16(x) side-product
    k_mm1<<<dim3(NN / 32, 2), 256, 0, stream>>>(x, linWT, lin_b, xlb4,
                                                use_xb ? xb : nullptr);
    k_scan<<<1, SCAN_T, 0, stream>>>(cnt, offs, cursor);
    k_scatter<<<(EE + 255) / 256, 256, 0, stream>>>(edge_index, edge_weight,
                                                    cursor, bucket, srcb, ewb);
    k_agg<<<NN, 256, 0, stream>>>(xlb4, edge_attr, ewb, bond_W, bond_b,
                                  srcb, offs, bucket, mean_b);
    // out = [mean | x] @ [linl; linr] + linl_b
    if (use_xb)
        k_mm2<1><<<dim3(MTOT / 128, 2), 256, 0, stream>>>(
            mean_b, xb, nullptr, WbT, linl_b, (float*)d_out);
    else
        k_mm2<0><<<dim3(MTOT / 128, 2), 256, 0, stream>>>(
            mean_b, nullptr, x, WbT, linl_b, (float*)d_out);
}

// Round 5
// 348.099 us; speedup vs baseline: 1.0804x; 1.0250x over previous
//
#include <hip/hip_runtime.h>
#include <math.h>

#define NN 20000
#define EE 100000
#define CC 256
#define EDM 16
#define RC 4
#define MTOT (RC * NN)   // 80000
#define NPB 8            // nodes per k_agg block
#define PREPB ((EE + 255) / 256)   // 391 count blocks
#define CONVB 10000                // x->bf16 conversion blocks (2048 elem each)

typedef __attribute__((ext_vector_type(8))) short short8;
typedef __attribute__((ext_vector_type(4))) float floatx4;

__device__ __forceinline__ unsigned short f2bf(float f) {
    union { float f; unsigned u; } v; v.f = f;
    unsigned r = v.u + 0x7FFF + ((v.u >> 16) & 1);   // RNE
    return (unsigned short)(r >> 16);
}
__device__ __forceinline__ float uif(unsigned u) {
    union { unsigned u; float f; } v; v.u = u;
    return v.f;
}

// GELU via A&S 7.1.27: erf(z) ~= 1 - (1 + a1 z + a2 z^2 + a3 z^3 + a4 z^4)^-4
__device__ __forceinline__ float gelu27(float v) {
    const float z  = fabsf(v) * 0.70710678118654752f;
    const float P  = fmaf(z, fmaf(z, fmaf(z, fmaf(z, 0.078108f, 0.000972f),
                           0.230389f), 0.278393f), 1.0f);
    const float r  = __builtin_amdgcn_rcpf(P);
    const float r2 = r * r;
    const float r4 = r2 * r2;
    const float h  = 0.5f * fabsf(v);
    return fmaf(0.5f, v, fmaf(-h, r4, h));   // 0.5v + h*(1 - r^4)
}

// async global->LDS, 16B per lane; LDS dest is wave-uniform base + lane*16
#define GLDS16(gp, lp)                                                        \
    __builtin_amdgcn_global_load_lds(                                         \
        (const __attribute__((address_space(1))) unsigned int*)(gp),          \
        (__attribute__((address_space(3))) unsigned int*)(lp), 16, 0, 0)

// ---------------------------------------------------------------------------
// prep: weight transpose+bf16 | per-dst edge count | x -> bf16 (xb) streaming
// ---------------------------------------------------------------------------
__global__ void k_prep(const float* __restrict__ lin_W,
                       const float* __restrict__ linl_W,
                       const float* __restrict__ linr_W,
                       unsigned short* __restrict__ linWT,
                       unsigned short* __restrict__ WbT,
                       const int* __restrict__ eidx,
                       int* __restrict__ cnt,
                       const float* __restrict__ x,
                       unsigned short* __restrict__ xb) {
    const int b = blockIdx.x;
    const int t = threadIdx.x;
    if (b < CC) {
        linWT[b * CC + t]      = f2bf(lin_W[t * CC + b]);
        WbT[b * 512 + t]       = f2bf(linl_W[t * CC + b]);
        WbT[b * 512 + 256 + t] = f2bf(linr_W[t * CC + b]);
    } else if (b < CC + PREPB) {
        int e = (b - CC) * 256 + t;
        if (e < EE) atomicAdd(cnt + eidx[EE + e], 1);
    } else {
        // x -> bf16 conversion, 2048 shorts per block, fully coalesced
        const size_t i8 = (size_t)(b - CC - PREPB) * 2048 + t * 8;
        const float4 v0 = *(const float4*)(x + i8);
        const float4 v1 = *(const float4*)(x + i8 + 4);
        uint4 p;
        p.x = (unsigned)f2bf(v0.x) | ((unsigned)f2bf(v0.y) << 16);
        p.y = (unsigned)f2bf(v0.z) | ((unsigned)f2bf(v0.w) << 16);
        p.z = (unsigned)f2bf(v1.x) | ((unsigned)f2bf(v1.y) << 16);
        p.w = (unsigned)f2bf(v1.z) | ((unsigned)f2bf(v1.w) << 16);
        *(uint4*)(xb + i8) = p;
    }
}

// ---------------------------------------------------------------------------
// mm1: xlb4[n][c][rc] (bf16, rc-interleaved) = x @ lin_W + lin_b
// 512 thr / 8 waves (2Mx4N), tile 128x128, BK=64, grid (625, 2).
// M rows permuted: local r -> global (r>>5)*NN + nn0 + (r&31)  (32 nodes x 4 rc)
// T2 swizzle via pre-swizzled per-lane GLOBAL chunk (lc8^lr8), linear GLDS dest,
// XOR on ds_read (rule #21). acc = 4x2 frags = 32 regs -> 4 waves/SIMD quantum.
// ---------------------------------------------------------------------------
template <int XB>
__global__ __launch_bounds__(512, 4) void k_mm1(const float* __restrict__ xf,
                                                const unsigned short* __restrict__ xb,
                                                const unsigned short* __restrict__ linWT,
                                                const float* __restrict__ lin_b,
                                                unsigned short* __restrict__ xlb4) {
    __shared__ __attribute__((aligned(16))) char SH[33280];  // As+Bs; epilogue E
    unsigned short* As = (unsigned short*)SH;
    unsigned short* Bs = As + 128 * 64;
    const int tid  = threadIdx.x;
    const int lane = tid & 63;
    const int wave = tid >> 6;      // 0..7
    const int wr   = wave >> 2;     // 0..1 (64-row half)
    const int wc   = wave & 3;      // 0..3 (32-col quarter)
    const int l15  = lane & 15;
    const int q4   = lane >> 4;
    const int lr8  = lane >> 3;
    const int lc8  = lane & 7;
    const int sc8  = (lc8 ^ lr8) * 8;   // swizzled source chunk (shorts)
    const int nn0  = blockIdx.x * 32;
    const int n0   = blockIdx.y * 128;

    floatx4 acc[4][2];
#pragma unroll
    for (int mt = 0; mt < 4; mt++)
#pragma unroll
        for (int nt = 0; nt < 2; nt++) acc[mt][nt] = (floatx4)0.0f;

    for (int kc = 0; kc < 256; kc += 64) {
        __syncthreads();
        // B tile (linWT rows = out cols, stride 256)
#pragma unroll
        for (int it = 0; it < 2; it++) {
            const int op = wave * 2 + it;   // 0..15
            GLDS16(linWT + (size_t)(n0 + op * 8 + lr8) * CC + kc + sc8,
                   Bs + op * 512);
        }
        // A tile (permuted rows)
        if (XB) {
#pragma unroll
            for (int it = 0; it < 2; it++) {
                const int op = wave * 2 + it;
                const int r  = op * 8 + lr8;
                const int grow = (r >> 5) * NN + nn0 + (r & 31);
                GLDS16(xb + (size_t)grow * CC + kc + sc8, As + op * 512);
            }
        } else {
#pragma unroll
            for (int w = 0; w < 2; w++) {
                const int q  = w * 512 + tid;
                const int r  = q >> 3;
                const int c8 = q & 7;
                const int grow = (r >> 5) * NN + nn0 + (r & 31);
                const float* s = xf + (size_t)grow * CC + kc + c8 * 8;
                float4 v0 = *(const float4*)(s);
                float4 v1 = *(const float4*)(s + 4);
                uint4 p;
                p.x = (unsigned)f2bf(v0.x) | ((unsigned)f2bf(v0.y) << 16);
                p.y = (unsigned)f2bf(v0.z) | ((unsigned)f2bf(v0.w) << 16);
                p.z = (unsigned)f2bf(v1.x) | ((unsigned)f2bf(v1.y) << 16);
                p.w = (unsigned)f2bf(v1.z) | ((unsigned)f2bf(v1.w) << 16);
                *(uint4*)(As + r * 64 + ((c8 ^ (r & 7)) * 8)) = p;
            }
        }
        __syncthreads();
#pragma unroll
        for (int kk = 0; kk < 64; kk += 32) {
            short8 a[4], b[2];
#pragma unroll
            for (int mt = 0; mt < 4; mt++) {
                const int row = wr * 64 + mt * 16 + l15;
                a[mt] = *(const short8*)(As + row * 64 +
                                         ((kk + q4 * 8) ^ ((row & 7) * 8)));
            }
#pragma unroll
            for (int nt = 0; nt < 2; nt++) {
                const int row = wc * 32 + nt * 16 + l15;
                b[nt] = *(const short8*)(Bs + row * 64 +
                                         ((kk + q4 * 8) ^ ((row & 7) * 8)));
            }
#pragma unroll
            for (int mt = 0; mt < 4; mt++)
#pragma unroll
                for (int nt = 0; nt < 2; nt++)
                    acc[mt][nt] = __builtin_amdgcn_mfma_f32_16x16x32_bf16(
                        a[mt], b[nt], acc[mt][nt], 0, 0, 0);
        }
    }
    // epilogue: stage [i(32)][cl(128)][rc(4)] bf16 (1040B row pad), then
    // coalesced 16B stores. rc = wr*2+(mt>>1), i = (mt&1)*16+q4*4+rr.
    __syncthreads();
    char* E = SH;
#pragma unroll
    for (int nt = 0; nt < 2; nt++) {
        const int cl = wc * 32 + nt * 16 + l15;
        const float bz = lin_b[n0 + cl];
#pragma unroll
        for (int m0 = 0; m0 < 2; m0++) {
#pragma unroll
            for (int rr = 0; rr < 4; rr++) {
                const int i = m0 * 16 + q4 * 4 + rr;
                const unsigned lo = f2bf(acc[m0][nt][rr] + bz);
                const unsigned hi = f2bf(acc[m0 + 2][nt][rr] + bz);
                *(unsigned*)(E + i * 1040 + cl * 8 + wr * 4) = lo | (hi << 16);
            }
        }
    }
    __syncthreads();
    char* gb = (char*)xlb4 + (size_t)nn0 * 2048 + (size_t)n0 * 8;
#pragma unroll
    for (int p = 0; p < 4; p++) {
        const int idx = p * 512 + tid;
        const int i   = idx >> 6;
        const int w   = (idx & 63) * 16;
        uint4 v = *(const uint4*)(E + i * 1040 + w);
        *(uint4*)(gb + (size_t)i * 2048 + w) = v;
    }
}

// ---------------------------------------------------------------------------
// mm2: out fp32 = [mean | x] @ WbT^T + linl_b.  K=512, same 8-wave structure.
// ---------------------------------------------------------------------------
template <int XB>
__global__ __launch_bounds__(512, 4) void k_mm2(const unsigned short* __restrict__ mean_b,
                                                const unsigned short* __restrict__ xb,
                                                const float* __restrict__ xf,
                                                const unsigned short* __restrict__ WbT,
                                                const float* __restrict__ bias,
                                                float* __restrict__ out) {
    __shared__ unsigned short As[128 * 64];
    __shared__ unsigned short Bs[128 * 64];
    const int tid  = threadIdx.x;
    const int lane = tid & 63;
    const int wave = tid >> 6;
    const int wr   = wave >> 2;
    const int wc   = wave & 3;
    const int l15  = lane & 15;
    const int q4   = lane >> 4;
    const int lr8  = lane >> 3;
    const int lc8  = lane & 7;
    const int sc8  = (lc8 ^ lr8) * 8;
    const int i0   = blockIdx.x * 128;
    const int n0   = blockIdx.y * 128;

    floatx4 acc[4][2];
#pragma unroll
    for (int mt = 0; mt < 4; mt++)
#pragma unroll
        for (int nt = 0; nt < 2; nt++) acc[mt][nt] = (floatx4)0.0f;

    for (int kc = 0; kc < 512; kc += 64) {
        __syncthreads();
        const int first = (kc < 256);
        const int kco   = first ? kc : kc - 256;
#pragma unroll
        for (int it = 0; it < 2; it++) {
            const int op = wave * 2 + it;
            GLDS16(WbT + (size_t)(n0 + op * 8 + lr8) * 512 + kc + sc8,
                   Bs + op * 512);
        }
        if (first || XB) {
            const unsigned short* ab = first ? mean_b : xb;
#pragma unroll
            for (int it = 0; it < 2; it++) {
                const int op = wave * 2 + it;
                GLDS16(ab + (size_t)(i0 + op * 8 + lr8) * CC + kco + sc8,
                       As + op * 512);
            }
        } else {
#pragma unroll
            for (int w = 0; w < 2; w++) {
                const int q  = w * 512 + tid;
                const int r  = q >> 3;
                const int c8 = q & 7;
                const float* s = xf + (size_t)(i0 + r) * CC + kco + c8 * 8;
                float4 v0 = *(const float4*)(s);
                float4 v1 = *(const float4*)(s + 4);
                uint4 p;
                p.x = (unsigned)f2bf(v0.x) | ((unsigned)f2bf(v0.y) << 16);
                p.y = (unsigned)f2bf(v0.z) | ((unsigned)f2bf(v0.w) << 16);
                p.z = (unsigned)f2bf(v1.x) | ((unsigned)f2bf(v1.y) << 16);
                p.w = (unsigned)f2bf(v1.z) | ((unsigned)f2bf(v1.w) << 16);
                *(uint4*)(As + r * 64 + ((c8 ^ (r & 7)) * 8)) = p;
            }
        }
        __syncthreads();
#pragma unroll
        for (int kk = 0; kk < 64; kk += 32) {
            short8 a[4], b[2];
#pragma unroll
            for (int mt = 0; mt < 4; mt++) {
                const int row = wr * 64 + mt * 16 + l15;
                a[mt] = *(const short8*)(As + row * 64 +
                                         ((kk + q4 * 8) ^ ((row & 7) * 8)));
            }
#pragma unroll
            for (int nt = 0; nt < 2; nt++) {
                const int row = wc * 32 + nt * 16 + l15;
                b[nt] = *(const short8*)(Bs + row * 64 +
                                         ((kk + q4 * 8) ^ ((row & 7) * 8)));
            }
#pragma unroll
            for (int mt = 0; mt < 4; mt++)
#pragma unroll
                for (int nt = 0; nt < 2; nt++)
                    acc[mt][nt] = __builtin_amdgcn_mfma_f32_16x16x32_bf16(
                        a[mt], b[nt], acc[mt][nt], 0, 0, 0);
        }
    }
#pragma unroll
    for (int nt = 0; nt < 2; nt++) {
        const int col = n0 + wc * 32 + nt * 16 + l15;
        const float bz = bias[col];
#pragma unroll
        for (int mt = 0; mt < 4; mt++) {
#pragma unroll
            for (int rr = 0; rr < 4; rr++) {
                const int row = i0 + wr * 64 + mt * 16 + q4 * 4 + rr;
                out[(size_t)row * CC + col] = acc[mt][nt][rr] + bz;
            }
        }
    }
}

// ---------------------------------------------------------------------------
// CSR scan + scatter
// ---------------------------------------------------------------------------
#define SCAN_T 1024
#define SCHUNK 20
__global__ __launch_bounds__(1024) void k_scan(const int* __restrict__ cnt,
                                               int* __restrict__ offs,
                                               int* __restrict__ cursor) {
    __shared__ int ps[SCAN_T];
    const int t = threadIdx.x;
    const int base = t * SCHUNK;
    int s = 0;
#pragma unroll
    for (int i = 0; i < SCHUNK; i++) {
        int idx = base + i;
        if (idx < NN) s += cnt[idx];
    }
    ps[t] = s;
    __syncthreads();
    for (int off = 1; off < SCAN_T; off <<= 1) {
        int v = (t >= off) ? ps[t - off] : 0;
        __syncthreads();
        ps[t] += v;
        __syncthreads();
    }
    int excl = (t == 0) ? 0 : ps[t - 1];
#pragma unroll
    for (int i = 0; i < SCHUNK; i++) {
        int idx = base + i;
        if (idx < NN) {
            offs[idx]   = excl;
            cursor[idx] = excl;
            excl += cnt[idx];
        }
    }
    if (t == SCAN_T - 1) offs[NN] = ps[SCAN_T - 1];
}

__global__ void k_scatter(const int* __restrict__ eidx,
                          const float* __restrict__ ew,
                          int* __restrict__ cursor,
                          int* __restrict__ bucket,
                          int* __restrict__ srcb,
                          float4* __restrict__ ewb) {
    int e = blockIdx.x * 256 + threadIdx.x;
    if (e < EE) {
        int d = eidx[EE + e];
        int p = atomicAdd(cursor + d, 1);
        bucket[p] = e;
        srcb[p]   = eidx[e];
        ewb[p]    = make_float4(ew[e], ew[EE + e], ew[2 * EE + e], ew[3 * EE + e]);
    }
}

// ---------------------------------------------------------------------------
// gather-mean: block = NPB nodes, thread = channel, 4 rc accumulators.
// bond_W hoist amortized over NPB nodes (~40 edges vs ~5).
// ---------------------------------------------------------------------------
__global__ __launch_bounds__(256) void k_agg(const unsigned short* __restrict__ xlb4,
                                             const float* __restrict__ edge_attr,
                                             const float4* __restrict__ ewb,
                                             const float* __restrict__ bond_W,
                                             const float* __restrict__ bond_b,
                                             const int* __restrict__ srcb,
                                             const int* __restrict__ offs,
                                             const int* __restrict__ bucket,
                                             unsigned short* __restrict__ mean_b) {
    const int c = threadIdx.x;
    const float bb = bond_b[c];
    float bw[EDM];
#pragma unroll
    for (int k = 0; k < EDM; k++) bw[k] = bond_W[k * CC + c];
    const int nbase = blockIdx.x * NPB;

    for (int nn = 0; nn < NPB; nn++) {
        const int n = nbase + nn;
        const int beg = offs[n], end = offs[n + 1];
        float a0 = 0.f, a1 = 0.f, a2 = 0.f, a3 = 0.f;

#pragma unroll 2
        for (int j = beg; j < end; j++) {
            const int e     = bucket[j];
            const int src   = srcb[j];
            const float4 w  = ewb[j];
            const float4* ea4 = (const float4*)(edge_attr + (size_t)e * EDM);
            const float4 q0 = ea4[0], q1 = ea4[1], q2 = ea4[2], q3 = ea4[3];
            float emb = bb;
            emb = fmaf(q0.x, bw[0],  emb); emb = fmaf(q0.y, bw[1],  emb);
            emb = fmaf(q0.z, bw[2],  emb); emb = fmaf(q0.w, bw[3],  emb);
            emb = fmaf(q1.x, bw[4],  emb); emb = fmaf(q1.y, bw[5],  emb);
            emb = fmaf(q1.z, bw[6],  emb); emb = fmaf(q1.w, bw[7],  emb);
            emb = fmaf(q2.x, bw[8],  emb); emb = fmaf(q2.y, bw[9],  emb);
            emb = fmaf(q2.z, bw[10], emb); emb = fmaf(q2.w, bw[11], emb);
            emb = fmaf(q3.x, bw[12], emb); emb = fmaf(q3.y, bw[13], emb);
            emb = fmaf(q3.z, bw[14], emb); emb = fmaf(q3.w, bw[15], emb);
            const uint2 u = *(const uint2*)(xlb4 + ((size_t)src * CC + c) * 4);
            const float v0 = uif(u.x << 16)          + emb;
            const float v1 = uif(u.x & 0xffff0000u)  + emb;
            const float v2 = uif(u.y << 16)          + emb;
            const float v3 = uif(u.y & 0xffff0000u)  + emb;
            a0 = fmaf(gelu27(v0), w.x, a0);
            a1 = fmaf(gelu27(v1), w.y, a1);
            a2 = fmaf(gelu27(v2), w.z, a2);
            a3 = fmaf(gelu27(v3), w.w, a3);
        }
        const float inv = 1.0f / fmaxf((float)(end - beg), 1.0f);
        const size_t ob = (size_t)n * CC + c;
        mean_b[ob]                       = f2bf(a0 * inv);
        mean_b[ob + (size_t)NN * CC]     = f2bf(a1 * inv);
        mean_b[ob + (size_t)2 * NN * CC] = f2bf(a2 * inv);
        mean_b[ob + (size_t)3 * NN * CC] = f2bf(a3 * inv);
    }
}

extern "C" void kernel_launch(void* const* d_in, const int* in_sizes, int n_in,
                              void* d_out, int out_size, void* d_ws, size_t ws_size,
                              hipStream_t stream) {
    (void)in_sizes; (void)n_in; (void)out_size;
    const float* x           = (const float*)d_in[0];
    const float* edge_attr   = (const float*)d_in[1];
    const float* edge_weight = (const float*)d_in[2];
    const float* lin_W       = (const float*)d_in[3];
    const float* lin_b       = (const float*)d_in[4];
    const float* linl_W      = (const float*)d_in[5];
    const float* linl_b      = (const float*)d_in[6];
    const float* linr_W      = (const float*)d_in[7];
    const float* bond_W      = (const float*)d_in[8];
    const float* bond_b      = (const float*)d_in[9];
    const int*   edge_index  = (const int*)d_in[10];

    unsigned short* xlb4  = (unsigned short*)d_ws;          // 80000*256 bf16 (rc-interleaved)
    unsigned short* linWT = xlb4 + (size_t)MTOT * CC;       // 256*256 bf16
    unsigned short* WbT   = linWT + CC * CC;                // 256*512 bf16
    int* cnt    = (int*)(WbT + CC * 512);                   // N
    int* offs   = cnt + NN;                                 // N+1
    int* cursor = offs + NN + 1;                            // N
    int* bucket = cursor + NN;                              // E
    uintptr_t mb_addr = (((uintptr_t)(bucket + EE)) + 255) & ~(uintptr_t)255;
    unsigned short* mean_b = (unsigned short*)mb_addr;      // 80000*256 bf16
    unsigned short* xb     = mean_b + (size_t)MTOT * CC;    // 80000*256 bf16 (optional)
    const size_t need_xb = ((uintptr_t)(xb + (size_t)MTOT * CC)) - (uintptr_t)d_ws;
    const int use_xb = (ws_size >= need_xb);

    // scratch in d_out: dead once k_mm2 runs (it overwrites ALL of d_out)
    float4* ewb  = (float4*)d_out;                          // E * 16B
    int*    srcb = (int*)(ewb + EE);                        // E * 4B

    hipMemsetAsync(cnt, 0, NN * sizeof(int), stream);

    k_prep<<<CC + PREPB + (use_xb ? CONVB : 0), 256, 0, stream>>>(
        lin_W, linl_W, linr_W, linWT, WbT, edge_index, cnt, x,
        use_xb ? xb : nullptr);
    // xlb4 = x @ lin_W + lin_b (rc-interleaved bf16)
    if (use_xb)
        k_mm1<1><<<dim3(NN / 32, 2), 512, 0, stream>>>(nullptr, xb, linWT, lin_b, xlb4);
    else
        k_mm1<0><<<dim3(NN / 32, 2), 512, 0, stream>>>(x, nullptr, linWT, lin_b, xlb4);
    k_scan<<<1, SCAN_T, 0, stream>>>(cnt, offs, cursor);
    k_scatter<<<PREPB, 256, 0, stream>>>(edge_index, edge_weight,
                                         cursor, bucket, srcb, ewb);
    k_agg<<<NN / NPB, 256, 0, stream>>>(xlb4, edge_attr, ewb, bond_W, bond_b,
                                        srcb, offs, bucket, mean_b);
    // out = [mean | x] @ [linl; linr] + linl_b
    if (use_xb)
        k_mm2<1><<<dim3(MTOT / 128, 2), 512, 0, stream>>>(
            mean_b, xb, nullptr, WbT, linl_b, (float*)d_out);
    else
        k_mm2<0><<<dim3(MTOT / 128, 2), 512, 0, stream>>>(
            mean_b, nullptr, x, WbT, linl_b, (float*)d_out);
}

// Round 6
// 344.961 us; speedup vs baseline: 1.0902x; 1.0091x over previous
//
#include <hip/hip_runtime.h>
#include <math.h>

#define NN 20000
#define EE 100000
#define CC 256
#define EDM 16
#define RC 4
#define MTOT (RC * NN)   // 80000
#define PREPB ((EE + 255) / 256)   // 391 count blocks
#define CONVB 10000                // x->bf16 conversion blocks (2048 elem each)

typedef __attribute__((ext_vector_type(8))) short short8;
typedef __attribute__((ext_vector_type(4))) float floatx4;

__device__ __forceinline__ unsigned short f2bf(float f) {
    union { float f; unsigned u; } v; v.f = f;
    unsigned r = v.u + 0x7FFF + ((v.u >> 16) & 1);   // RNE
    return (unsigned short)(r >> 16);
}
__device__ __forceinline__ float uif(unsigned u) {
    union { unsigned u; float f; } v; v.u = u;
    return v.f;
}

// GELU via A&S 7.1.27: erf(z) ~= 1 - (1 + a1 z + a2 z^2 + a3 z^3 + a4 z^4)^-4
__device__ __forceinline__ float gelu27(float v) {
    const float z  = fabsf(v) * 0.70710678118654752f;
    const float P  = fmaf(z, fmaf(z, fmaf(z, fmaf(z, 0.078108f, 0.000972f),
                           0.230389f), 0.278393f), 1.0f);
    const float r  = __builtin_amdgcn_rcpf(P);
    const float r2 = r * r;
    const float r4 = r2 * r2;
    const float h  = 0.5f * fabsf(v);
    return fmaf(0.5f, v, fmaf(-h, r4, h));   // 0.5v + h*(1 - r^4)
}

// async global->LDS, 16B per lane; LDS dest is wave-uniform base + lane*16
#define GLDS16(gp, lp)                                                        \
    __builtin_amdgcn_global_load_lds(                                         \
        (const __attribute__((address_space(1))) unsigned int*)(gp),          \
        (__attribute__((address_space(3))) unsigned int*)(lp), 16, 0, 0)

// ---------------------------------------------------------------------------
// prep: weight transpose+bf16 | per-dst edge count | x -> bf16 (xb) streaming
// ---------------------------------------------------------------------------
__global__ void k_prep(const float* __restrict__ lin_W,
                       const float* __restrict__ linl_W,
                       const float* __restrict__ linr_W,
                       unsigned short* __restrict__ linWT,
                       unsigned short* __restrict__ WbT,
                       const int* __restrict__ eidx,
                       int* __restrict__ cnt,
                       const float* __restrict__ x,
                       unsigned short* __restrict__ xb) {
    const int b = blockIdx.x;
    const int t = threadIdx.x;
    if (b < CC) {
        linWT[b * CC + t]      = f2bf(lin_W[t * CC + b]);
        WbT[b * 512 + t]       = f2bf(linl_W[t * CC + b]);
        WbT[b * 512 + 256 + t] = f2bf(linr_W[t * CC + b]);
    } else if (b < CC + PREPB) {
        int e = (b - CC) * 256 + t;
        if (e < EE) atomicAdd(cnt + eidx[EE + e], 1);
    } else {
        // x -> bf16 conversion, 2048 shorts per block, fully coalesced
        const size_t i8 = (size_t)(b - CC - PREPB) * 2048 + t * 8;
        const float4 v0 = *(const float4*)(x + i8);
        const float4 v1 = *(const float4*)(x + i8 + 4);
        uint4 p;
        p.x = (unsigned)f2bf(v0.x) | ((unsigned)f2bf(v0.y) << 16);
        p.y = (unsigned)f2bf(v0.z) | ((unsigned)f2bf(v0.w) << 16);
        p.z = (unsigned)f2bf(v1.x) | ((unsigned)f2bf(v1.y) << 16);
        p.w = (unsigned)f2bf(v1.z) | ((unsigned)f2bf(v1.w) << 16);
        *(uint4*)(xb + i8) = p;
    }
}

// ---------------------------------------------------------------------------
// mm1: xlb4[n][c][rc] (bf16, rc-interleaved) = x @ lin_W + lin_b
// 512 thr / 8 waves (2Mx4N), tile 128x128, BK=64, grid (625, 2).
// M rows permuted: local r -> global (r>>5)*NN + nn0 + (r&31)  (32 nodes x 4 rc)
// T2 swizzle via pre-swizzled per-lane GLOBAL chunk (lc8^lr8), linear GLDS dest,
// XOR on ds_read (rule #21). acc = 4x2 frags = 32 regs -> 4 waves/SIMD quantum.
// ---------------------------------------------------------------------------
template <int XB>
__global__ __launch_bounds__(512, 4) void k_mm1(const float* __restrict__ xf,
                                                const unsigned short* __restrict__ xb,
                                                const unsigned short* __restrict__ linWT,
                                                const float* __restrict__ lin_b,
                                                unsigned short* __restrict__ xlb4) {
    __shared__ __attribute__((aligned(16))) char SH[33280];  // As+Bs; epilogue E
    unsigned short* As = (unsigned short*)SH;
    unsigned short* Bs = As + 128 * 64;
    const int tid  = threadIdx.x;
    const int lane = tid & 63;
    const int wave = tid >> 6;      // 0..7
    const int wr   = wave >> 2;     // 0..1 (64-row half)
    const int wc   = wave & 3;      // 0..3 (32-col quarter)
    const int l15  = lane & 15;
    const int q4   = lane >> 4;
    const int lr8  = lane >> 3;
    const int lc8  = lane & 7;
    const int sc8  = (lc8 ^ lr8) * 8;   // swizzled source chunk (shorts)
    const int nn0  = blockIdx.x * 32;
    const int n0   = blockIdx.y * 128;

    floatx4 acc[4][2];
#pragma unroll
    for (int mt = 0; mt < 4; mt++)
#pragma unroll
        for (int nt = 0; nt < 2; nt++) acc[mt][nt] = (floatx4)0.0f;

    for (int kc = 0; kc < 256; kc += 64) {
        __syncthreads();
        // B tile (linWT rows = out cols, stride 256)
#pragma unroll
        for (int it = 0; it < 2; it++) {
            const int op = wave * 2 + it;   // 0..15
            GLDS16(linWT + (size_t)(n0 + op * 8 + lr8) * CC + kc + sc8,
                   Bs + op * 512);
        }
        // A tile (permuted rows)
        if (XB) {
#pragma unroll
            for (int it = 0; it < 2; it++) {
                const int op = wave * 2 + it;
                const int r  = op * 8 + lr8;
                const int grow = (r >> 5) * NN + nn0 + (r & 31);
                GLDS16(xb + (size_t)grow * CC + kc + sc8, As + op * 512);
            }
        } else {
#pragma unroll
            for (int w = 0; w < 2; w++) {
                const int q  = w * 512 + tid;
                const int r  = q >> 3;
                const int c8 = q & 7;
                const int grow = (r >> 5) * NN + nn0 + (r & 31);
                const float* s = xf + (size_t)grow * CC + kc + c8 * 8;
                float4 v0 = *(const float4*)(s);
                float4 v1 = *(const float4*)(s + 4);
                uint4 p;
                p.x = (unsigned)f2bf(v0.x) | ((unsigned)f2bf(v0.y) << 16);
                p.y = (unsigned)f2bf(v0.z) | ((unsigned)f2bf(v0.w) << 16);
                p.z = (unsigned)f2bf(v1.x) | ((unsigned)f2bf(v1.y) << 16);
                p.w = (unsigned)f2bf(v1.z) | ((unsigned)f2bf(v1.w) << 16);
                *(uint4*)(As + r * 64 + ((c8 ^ (r & 7)) * 8)) = p;
            }
        }
        __syncthreads();
#pragma unroll
        for (int kk = 0; kk < 64; kk += 32) {
            short8 a[4], b[2];
#pragma unroll
            for (int mt = 0; mt < 4; mt++) {
                const int row = wr * 64 + mt * 16 + l15;
                a[mt] = *(const short8*)(As + row * 64 +
                                         ((kk + q4 * 8) ^ ((row & 7) * 8)));
            }
#pragma unroll
            for (int nt = 0; nt < 2; nt++) {
                const int row = wc * 32 + nt * 16 + l15;
                b[nt] = *(const short8*)(Bs + row * 64 +
                                         ((kk + q4 * 8) ^ ((row & 7) * 8)));
            }
#pragma unroll
            for (int mt = 0; mt < 4; mt++)
#pragma unroll
                for (int nt = 0; nt < 2; nt++)
                    acc[mt][nt] = __builtin_amdgcn_mfma_f32_16x16x32_bf16(
                        a[mt], b[nt], acc[mt][nt], 0, 0, 0);
        }
    }
    // epilogue: stage [i(32)][cl(128)][rc(4)] bf16 (1040B row pad), then
    // coalesced 16B stores. rc = wr*2+(mt>>1), i = (mt&1)*16+q4*4+rr.
    __syncthreads();
    char* E = SH;
#pragma unroll
    for (int nt = 0; nt < 2; nt++) {
        const int cl = wc * 32 + nt * 16 + l15;
        const float bz = lin_b[n0 + cl];
#pragma unroll
        for (int m0 = 0; m0 < 2; m0++) {
#pragma unroll
            for (int rr = 0; rr < 4; rr++) {
                const int i = m0 * 16 + q4 * 4 + rr;
                const unsigned lo = f2bf(acc[m0][nt][rr] + bz);
                const unsigned hi = f2bf(acc[m0 + 2][nt][rr] + bz);
                *(unsigned*)(E + i * 1040 + cl * 8 + wr * 4) = lo | (hi << 16);
            }
        }
    }
    __syncthreads();
    char* gb = (char*)xlb4 + (size_t)nn0 * 2048 + (size_t)n0 * 8;
#pragma unroll
    for (int p = 0; p < 4; p++) {
        const int idx = p * 512 + tid;
        const int i   = idx >> 6;
        const int w   = (idx & 63) * 16;
        uint4 v = *(const uint4*)(E + i * 1040 + w);
        *(uint4*)(gb + (size_t)i * 2048 + w) = v;
    }
}

// ---------------------------------------------------------------------------
// mm2: out fp32 = [mean | x] @ WbT^T + linl_b.  K=512, same 8-wave structure.
// ---------------------------------------------------------------------------
template <int XB>
__global__ __launch_bounds__(512, 4) void k_mm2(const unsigned short* __restrict__ mean_b,
                                                const unsigned short* __restrict__ xb,
                                                const float* __restrict__ xf,
                                                const unsigned short* __restrict__ WbT,
                                                const float* __restrict__ bias,
                                                float* __restrict__ out) {
    __shared__ unsigned short As[128 * 64];
    __shared__ unsigned short Bs[128 * 64];
    const int tid  = threadIdx.x;
    const int lane = tid & 63;
    const int wave = tid >> 6;
    const int wr   = wave >> 2;
    const int wc   = wave & 3;
    const int l15  = lane & 15;
    const int q4   = lane >> 4;
    const int lr8  = lane >> 3;
    const int lc8  = lane & 7;
    const int sc8  = (lc8 ^ lr8) * 8;
    const int i0   = blockIdx.x * 128;
    const int n0   = blockIdx.y * 128;

    floatx4 acc[4][2];
#pragma unroll
    for (int mt = 0; mt < 4; mt++)
#pragma unroll
        for (int nt = 0; nt < 2; nt++) acc[mt][nt] = (floatx4)0.0f;

    for (int kc = 0; kc < 512; kc += 64) {
        __syncthreads();
        const int first = (kc < 256);
        const int kco   = first ? kc : kc - 256;
#pragma unroll
        for (int it = 0; it < 2; it++) {
            const int op = wave * 2 + it;
            GLDS16(WbT + (size_t)(n0 + op * 8 + lr8) * 512 + kc + sc8,
                   Bs + op * 512);
        }
        if (first || XB) {
            const unsigned short* ab = first ? mean_b : xb;
#pragma unroll
            for (int it = 0; it < 2; it++) {
                const int op = wave * 2 + it;
                GLDS16(ab + (size_t)(i0 + op * 8 + lr8) * CC + kco + sc8,
                       As + op * 512);
            }
        } else {
#pragma unroll
            for (int w = 0; w < 2; w++) {
                const int q  = w * 512 + tid;
                const int r  = q >> 3;
                const int c8 = q & 7;
                const float* s = xf + (size_t)(i0 + r) * CC + kco + c8 * 8;
                float4 v0 = *(const float4*)(s);
                float4 v1 = *(const float4*)(s + 4);
                uint4 p;
                p.x = (unsigned)f2bf(v0.x) | ((unsigned)f2bf(v0.y) << 16);
                p.y = (unsigned)f2bf(v0.z) | ((unsigned)f2bf(v0.w) << 16);
                p.z = (unsigned)f2bf(v1.x) | ((unsigned)f2bf(v1.y) << 16);
                p.w = (unsigned)f2bf(v1.z) | ((unsigned)f2bf(v1.w) << 16);
                *(uint4*)(As + r * 64 + ((c8 ^ (r & 7)) * 8)) = p;
            }
        }
        __syncthreads();
#pragma unroll
        for (int kk = 0; kk < 64; kk += 32) {
            short8 a[4], b[2];
#pragma unroll
            for (int mt = 0; mt < 4; mt++) {
                const int row = wr * 64 + mt * 16 + l15;
                a[mt] = *(const short8*)(As + row * 64 +
                                         ((kk + q4 * 8) ^ ((row & 7) * 8)));
            }
#pragma unroll
            for (int nt = 0; nt < 2; nt++) {
                const int row = wc * 32 + nt * 16 + l15;
                b[nt] = *(const short8*)(Bs + row * 64 +
                                         ((kk + q4 * 8) ^ ((row & 7) * 8)));
            }
#pragma unroll
            for (int mt = 0; mt < 4; mt++)
#pragma unroll
                for (int nt = 0; nt < 2; nt++)
                    acc[mt][nt] = __builtin_amdgcn_mfma_f32_16x16x32_bf16(
                        a[mt], b[nt], acc[mt][nt], 0, 0, 0);
        }
    }
#pragma unroll
    for (int nt = 0; nt < 2; nt++) {
        const int col = n0 + wc * 32 + nt * 16 + l15;
        const float bz = bias[col];
#pragma unroll
        for (int mt = 0; mt < 4; mt++) {
#pragma unroll
            for (int rr = 0; rr < 4; rr++) {
                const int row = i0 + wr * 64 + mt * 16 + q4 * 4 + rr;
                out[(size_t)row * CC + col] = acc[mt][nt][rr] + bz;
            }
        }
    }
}

// ---------------------------------------------------------------------------
// CSR scan + scatter
// ---------------------------------------------------------------------------
#define SCAN_T 1024
#define SCHUNK 20
__global__ __launch_bounds__(1024) void k_scan(const int* __restrict__ cnt,
                                               int* __restrict__ offs,
                                               int* __restrict__ cursor) {
    __shared__ int ps[SCAN_T];
    const int t = threadIdx.x;
    const int base = t * SCHUNK;
    int s = 0;
#pragma unroll
    for (int i = 0; i < SCHUNK; i++) {
        int idx = base + i;
        if (idx < NN) s += cnt[idx];
    }
    ps[t] = s;
    __syncthreads();
    for (int off = 1; off < SCAN_T; off <<= 1) {
        int v = (t >= off) ? ps[t - off] : 0;
        __syncthreads();
        ps[t] += v;
        __syncthreads();
    }
    int excl = (t == 0) ? 0 : ps[t - 1];
#pragma unroll
    for (int i = 0; i < SCHUNK; i++) {
        int idx = base + i;
        if (idx < NN) {
            offs[idx]   = excl;
            cursor[idx] = excl;
            excl += cnt[idx];
        }
    }
    if (t == SCAN_T - 1) offs[NN] = ps[SCAN_T - 1];
}

__global__ void k_scatter(const int* __restrict__ eidx,
                          const float* __restrict__ ew,
                          int* __restrict__ cursor,
                          int* __restrict__ bucket,
                          int* __restrict__ srcb,
                          float4* __restrict__ ewb) {
    int e = blockIdx.x * 256 + threadIdx.x;
    if (e < EE) {
        int d = eidx[EE + e];
        int p = atomicAdd(cursor + d, 1);
        bucket[p] = e;
        srcb[p]   = eidx[e];
        ewb[p]    = make_float4(ew[e], ew[EE + e], ew[2 * EE + e], ew[3 * EE + e]);
    }
}

// ---------------------------------------------------------------------------
// gather-mean: block = 1 node (grid NN), thread = channel, 4 rc accumulators.
// [round-4 config: 20000 fine-grained blocks -> best measured occupancy/TLP]
// ---------------------------------------------------------------------------
__global__ __launch_bounds__(256) void k_agg(const unsigned short* __restrict__ xlb4,
                                             const float* __restrict__ edge_attr,
                                             const float4* __restrict__ ewb,
                                             const float* __restrict__ bond_W,
                                             const float* __restrict__ bond_b,
                                             const int* __restrict__ srcb,
                                             const int* __restrict__ offs,
                                             const int* __restrict__ bucket,
                                             unsigned short* __restrict__ mean_b) {
    const int n = blockIdx.x;
    const int c = threadIdx.x;
    const int beg = offs[n], end = offs[n + 1];
    const float bb = bond_b[c];
    float bw[EDM];
#pragma unroll
    for (int k = 0; k < EDM; k++) bw[k] = bond_W[k * CC + c];

    float a0 = 0.f, a1 = 0.f, a2 = 0.f, a3 = 0.f;

#pragma unroll 2
    for (int j = beg; j < end; j++) {
        const int e     = bucket[j];
        const int src   = srcb[j];
        const float4 w  = ewb[j];
        const float4* ea4 = (const float4*)(edge_attr + (size_t)e * EDM);
        const float4 q0 = ea4[0], q1 = ea4[1], q2 = ea4[2], q3 = ea4[3];
        float emb = bb;
        emb = fmaf(q0.x, bw[0],  emb); emb = fmaf(q0.y, bw[1],  emb);
        emb = fmaf(q0.z, bw[2],  emb); emb = fmaf(q0.w, bw[3],  emb);
        emb = fmaf(q1.x, bw[4],  emb); emb = fmaf(q1.y, bw[5],  emb);
        emb = fmaf(q1.z, bw[6],  emb); emb = fmaf(q1.w, bw[7],  emb);
        emb = fmaf(q2.x, bw[8],  emb); emb = fmaf(q2.y, bw[9],  emb);
        emb = fmaf(q2.z, bw[10], emb); emb = fmaf(q2.w, bw[11], emb);
        emb = fmaf(q3.x, bw[12], emb); emb = fmaf(q3.y, bw[13], emb);
        emb = fmaf(q3.z, bw[14], emb); emb = fmaf(q3.w, bw[15], emb);
        const uint2 u = *(const uint2*)(xlb4 + ((size_t)src * CC + c) * 4);
        const float v0 = uif(u.x << 16)          + emb;
        const float v1 = uif(u.x & 0xffff0000u)  + emb;
        const float v2 = uif(u.y << 16)          + emb;
        const float v3 = uif(u.y & 0xffff0000u)  + emb;
        a0 = fmaf(gelu27(v0), w.x, a0);
        a1 = fmaf(gelu27(v1), w.y, a1);
        a2 = fmaf(gelu27(v2), w.z, a2);
        a3 = fmaf(gelu27(v3), w.w, a3);
    }
    const float inv = 1.0f / fmaxf((float)(end - beg), 1.0f);
    const size_t ob = (size_t)n * CC + c;
    mean_b[ob]                       = f2bf(a0 * inv);
    mean_b[ob + (size_t)NN * CC]     = f2bf(a1 * inv);
    mean_b[ob + (size_t)2 * NN * CC] = f2bf(a2 * inv);
    mean_b[ob + (size_t)3 * NN * CC] = f2bf(a3 * inv);
}

extern "C" void kernel_launch(void* const* d_in, const int* in_sizes, int n_in,
                              void* d_out, int out_size, void* d_ws, size_t ws_size,
                              hipStream_t stream) {
    (void)in_sizes; (void)n_in; (void)out_size;
    const float* x           = (const float*)d_in[0];
    const float* edge_attr   = (const float*)d_in[1];
    const float* edge_weight = (const float*)d_in[2];
    const float* lin_W       = (const float*)d_in[3];
    const float* lin_b       = (const float*)d_in[4];
    const float* linl_W      = (const float*)d_in[5];
    const float* linl_b      = (const float*)d_in[6];
    const float* linr_W      = (const float*)d_in[7];
    const float* bond_W      = (const float*)d_in[8];
    const float* bond_b      = (const float*)d_in[9];
    const int*   edge_index  = (const int*)d_in[10];

    unsigned short* xlb4  = (unsigned short*)d_ws;          // 80000*256 bf16 (rc-interleaved)
    unsigned short* linWT = xlb4 + (size_t)MTOT * CC;       // 256*256 bf16
    unsigned short* WbT   = linWT + CC * CC;                // 256*512 bf16
    int* cnt    = (int*)(WbT + CC * 512);                   // N
    int* offs   = cnt + NN;                                 // N+1
    int* cursor = offs + NN + 1;                            // N
    int* bucket = cursor + NN;                              // E
    uintptr_t mb_addr = (((uintptr_t)(bucket + EE)) + 255) & ~(uintptr_t)255;
    unsigned short* mean_b = (unsigned short*)mb_addr;      // 80000*256 bf16
    unsigned short* xb     = mean_b + (size_t)MTOT * CC;    // 80000*256 bf16 (optional)
    const size_t need_xb = ((uintptr_t)(xb + (size_t)MTOT * CC)) - (uintptr_t)d_ws;
    const int use_xb = (ws_size >= need_xb);

    // scratch in d_out: dead once k_mm2 runs (it overwrites ALL of d_out)
    float4* ewb  = (float4*)d_out;                          // E * 16B
    int*    srcb = (int*)(ewb + EE);                        // E * 4B

    hipMemsetAsync(cnt, 0, NN * sizeof(int), stream);

    k_prep<<<CC + PREPB + (use_xb ? CONVB : 0), 256, 0, stream>>>(
        lin_W, linl_W, linr_W, linWT, WbT, edge_index, cnt, x,
        use_xb ? xb : nullptr);
    // xlb4 = x @ lin_W + lin_b (rc-interleaved bf16)
    if (use_xb)
        k_mm1<1><<<dim3(NN / 32, 2), 512, 0, stream>>>(nullptr, xb, linWT, lin_b, xlb4);
    else
        k_mm1<0><<<dim3(NN / 32, 2), 512, 0, stream>>>(x, nullptr, linWT, lin_b, xlb4);
    k_scan<<<1, SCAN_T, 0, stream>>>(cnt, offs, cursor);
    k_scatter<<<PREPB, 256, 0, stream>>>(edge_index, edge_weight,
                                         cursor, bucket, srcb, ewb);
    k_agg<<<NN, 256, 0, stream>>>(xlb4, edge_attr, ewb, bond_W, bond_b,
                                  srcb, offs, bucket, mean_b);
    // out = [mean | x] @ [linl; linr] + linl_b
    if (use_xb)
        k_mm2<1><<<dim3(MTOT / 128, 2), 512, 0, stream>>>(
            mean_b, xb, nullptr, WbT, linl_b, (float*)d_out);
    else
        k_mm2<0><<<dim3(MTOT / 128, 2), 512, 0, stream>>>(
            mean_b, nullptr, x, WbT, linl_b, (float*)d_out);
}